// Round 8
// baseline (5622.379 us; speedup 1.0000x reference)
//
#include <hip/hip_runtime.h>
#include <cstddef>
#include <cstdint>

#define BB 64
#define TT 512
#define HH 1024
#define DD 300
#define NTH 256
#define NBLK 64               // halved: each block owns 16 h-indices
#define HB 16
#define NTN 4                 // 4 N-tiles of 16 cols; Ntile == gate
#define XPAD 320
#define KS_X 10
#define KS_H 32
#define BN_EPS 1e-5f

typedef short short8 __attribute__((ext_vector_type(8)));
typedef float f32x4 __attribute__((ext_vector_type(4)));
typedef unsigned u32x2 __attribute__((ext_vector_type(2)));

__device__ __forceinline__ float sigmoid_f(float v) {
  v = fminf(fmaxf(v, -30.f), 30.f);
  return 1.f / (1.f + __expf(-v));
}
__device__ __forceinline__ float tanh_f(float v) {
  float e = __expf(fminf(fmaxf(2.f * v, -30.f), 30.f));
  return (e - 1.f) / (e + 1.f);
}
__device__ __forceinline__ unsigned short tobf(float f) {
  unsigned u = __float_as_uint(f);
  u += 0x7fffu + ((u >> 16) & 1u);
  return (unsigned short)(u >> 16);
}

// ---- all in-loop vmem is inline asm; counted-vmcnt ledger relies on
// in-order vmcnt retirement (issue order), mixed sc/plain included.
__device__ __forceinline__ void ldA_sc(const void* p, short8& d) {
  asm volatile("global_load_dwordx4 %0, %1, off sc0 sc1"
               : "=v"(d) : "v"(p) : "memory");
}
__device__ __forceinline__ void ldA_nc(const void* p, short8& d) {
  asm volatile("global_load_dwordx4 %0, %1, off"
               : "=v"(d) : "v"(p) : "memory");
}
__device__ __forceinline__ void ld4_sc(const void* p, f32x4& d) {
  asm volatile("global_load_dwordx4 %0, %1, off sc0 sc1"
               : "=v"(d) : "v"(p) : "memory");
}
__device__ __forceinline__ unsigned ld_sc(const void* p) {
  unsigned v;
  asm volatile("global_load_dword %0, %1, off sc0 sc1\n\ts_waitcnt vmcnt(0)"
               : "=v"(v) : "v"(p) : "memory");
  return v;
}
__device__ __forceinline__ void st_sc32(void* p, unsigned v) {  // drained
  asm volatile("global_store_dword %0, %1, off sc0 sc1\n\ts_waitcnt vmcnt(0)"
               :: "v"(p), "v"(v) : "memory");
}
__device__ __forceinline__ void st_sc32_nd(void* p, unsigned v) {  // no drain
  asm volatile("global_store_dword %0, %1, off sc0 sc1"
               :: "v"(p), "v"(v) : "memory");
}
__device__ __forceinline__ void st2_sc(void* p, u32x2 v) {  // drained
  asm volatile("global_store_dwordx2 %0, %1, off sc0 sc1\n\ts_waitcnt vmcnt(0)"
               :: "v"(p), "v"(v) : "memory");
}
#define WAITV(N)                                                   \
  do {                                                             \
    asm volatile("s_waitcnt vmcnt(" #N ")" ::: "memory");          \
    __builtin_amdgcn_sched_barrier(0);                             \
  } while (0)

__device__ __forceinline__ f32x4 mfma16(short8 a, short8 b, f32x4 c) {
  return __builtin_amdgcn_mfma_f32_16x16x32_bf16(a, b, c, 0, 0, 0);
}

// r5-proven poll: wave0 reads all 64 slots (1 dword/lane), block-wide AND.
// Non-wave0 waves carry no vmem here, so nothing of theirs gets drained.
__device__ __forceinline__ void poll_ge(const unsigned* slots, int tid, unsigned ep) {
  int it = 0;
  for (;;) {
    int ok = 1;
    if (tid < 64) ok = (ld_sc(&slots[tid]) >= ep) ? 1 : 0;
    if (__syncthreads_and(ok)) break;
    if (++it > (1 << 20)) break;  // valve: fail visibly, never hang
    if (it > 2) __builtin_amdgcn_s_sleep(1);
  }
}

__global__ void init_k(unsigned* __restrict__ base, int ndw) {
  int idx = blockIdx.x * blockDim.x + threadIdx.x;
  for (int i = idx; i < ndw; i += gridDim.x * blockDim.x) st_sc32(base + i, 0u);
}

// x [b][t][d] f32 -> xbf [t][b][XPAD] bf16 (zero-padded)
__global__ void xcvt_k(const float* __restrict__ x, unsigned short* __restrict__ xbf) {
  const int total = TT * BB * XPAD;
  for (int idx = blockIdx.x * blockDim.x + threadIdx.x; idx < total;
       idx += gridDim.x * blockDim.x) {
    int kx = idx % XPAD;
    int tb = idx / XPAD;
    int b = tb % BB, t = tb / BB;
    float v = (kx < DD) ? x[(size_t)b * (TT * DD) + (size_t)t * DD + kx] : 0.f;
    xbf[idx] = tobf(v);
  }
}

// W_ih -> bf16 B-fragments in ws: wfr[((bk*KS_X+ks)*NTN+nt)*64+ll] (short8)
__global__ void wihfrag_k(const float* __restrict__ Wih,
                          unsigned short* __restrict__ wfr) {
  int idx = blockIdx.x * blockDim.x + threadIdx.x;
  const int total = NBLK * KS_X * NTN * 64;
  for (; idx < total; idx += gridDim.x * blockDim.x) {
    int ll = idx & 63;
    int rest = idx >> 6;
    int nt = rest & 3;
    rest >>= 2;
    int ks = rest % KS_X, bk = rest / KS_X;
    int r = nt * HH + bk * HB + (ll & 15);   // Ntile == gate
    int k0 = ks * 32 + (ll >> 4) * 8;
    short8 pk;
#pragma unroll
    for (int e = 0; e < 8; ++e)
      pk[e] = (k0 + e < DD) ? (short)tobf(Wih[(size_t)r * DD + k0 + e]) : (short)0;
    *(short8*)(wfr + (size_t)idx * 8) = pk;
  }
}

__global__ void __launch_bounds__(NTH, 1)
lstm_mfma(const float* __restrict__ Whh, const float* __restrict__ bih,
          const float* __restrict__ bhh, const float* __restrict__ gammap,
          const float* __restrict__ betap, const float* __restrict__ maskp,
          const float* __restrict__ tlbl, const float* __restrict__ fcw,
          const float* __restrict__ fcb, const unsigned short* __restrict__ xbf,
          const unsigned short* __restrict__ wfrag,
          unsigned short* __restrict__ hbuf, float* __restrict__ partial,
          unsigned* __restrict__ slots, float* __restrict__ outp) {
  // W_hh B-frags: Wlds[nt][ks][lane] = 8 bf16 of
  // B[k=ks*32+(lane>>4)*8+e][col = nt*16+(lane&15)] (Ntile==gate). 128 KB.
  __shared__ short8 Wlds[NTN][KS_H][64];  // 128 KB
  __shared__ float Cs[64][65];            // 16.6 KB (+1 pad)
  __shared__ float red_s[4][64];          // 1 KB   (total ~145.9 KB)

  const int tid = threadIdx.x;
  const int w = tid >> 6, l = tid & 63;
  const int blk = blockIdx.x;
  const int hb0 = blk * HB;

  // ---- stage W_hh as bf16 fragments (once) ----
  for (int idx = tid; idx < NTN * KS_H * 64; idx += NTH) {
    int nt = idx / (KS_H * 64);
    int rem = idx % (KS_H * 64);
    int ks = rem >> 6, ll = rem & 63;
    int r = nt * HH + hb0 + (ll & 15);
    int k0 = ks * 32 + (ll >> 4) * 8;
    const float* src = Whh + (size_t)r * HH + k0;
    f32x4 u0 = *(const f32x4*)src;
    f32x4 u1 = *(const f32x4*)(src + 4);
    short8 pk;
    pk[0] = (short)tobf(u0.x); pk[1] = (short)tobf(u0.y);
    pk[2] = (short)tobf(u0.z); pk[3] = (short)tobf(u0.w);
    pk[4] = (short)tobf(u1.x); pk[5] = (short)tobf(u1.y);
    pk[6] = (short)tobf(u1.z); pk[7] = (short)tobf(u1.w);
    Wlds[nt][ks][ll] = pk;
  }

  // ---- MFMA roles: wave = M-tile (16 batch rows), all 4 N-tiles ----
  const int row = w * 16 + (l & 15);
  const int lk16 = l >> 4;

  // per-col bias folded into acc init (col = nt*16 + (l&15), gate = nt)
  float bcol[NTN];
#pragma unroll
  for (int nt = 0; nt < NTN; ++nt)
    bcol[nt] = bih[nt * HH + hb0 + (l & 15)] + bhh[nt * HH + hb0 + (l & 15)];

  // ---- pointwise roles: lane = batch, thread handles cols j = 4w..4w+3 ----
  const int b = l;
  float gam[4], bet[4], msk[4], fw[4], creg[4], pool[4];
#pragma unroll
  for (int i = 0; i < 4; ++i) {
    int j = 4 * w + i;
    gam[i] = gammap[hb0 + j];
    bet[i] = betap[hb0 + j];
    msk[i] = maskp[(size_t)b * HH + hb0 + j];
    fw[i] = fcw[hb0 + j];
    creg[i] = 0.f;
    pool[i] = -3.4e38f;
  }

  const unsigned short* wfb = wfrag + (size_t)blk * (KS_X * NTN * 64 * 8);
  __syncthreads();  // Wlds visible; all staging vmem retired (values consumed)

  for (int s = 0; s < TT; ++s) {
    const unsigned short* hc = hbuf + (size_t)(s & 1) * (BB * HH);
    unsigned short* hnx = hbuf + (size_t)((s + 1) & 1) * (BB * HH);

    // detect h_s (all waves enter with vmcnt==0: publish drained last iter)
    poll_ge(slots, tid, (unsigned)s);

    // h image layout: [seg=64][b=64][16 cols] bf16; global k = seg*16+col.
    // A-frag addr (ushorts): (k0>>4)*1024 + row*16 + (k0&15), k0=ks*32+lk16*8.
    const unsigned short* phb =
        hc + (size_t)(lk16 >> 1) * 1024 + row * 16 + (lk16 & 1) * 8;
    short8 ha[KS_H], xa[KS_X], xb[20];

    // ---- vmcnt ledger (in-order retirement). queue oldest->youngest ----
    #pragma unroll
    for (int i = 0; i < 8; ++i) ldA_sc(phb + i * 2048, ha[i]);        // hc0: 8
    #pragma unroll
    for (int i = 8; i < 16; ++i) ldA_sc(phb + i * 2048, ha[i]);       // hc1: 16
    {
      const unsigned short* px = xbf + ((size_t)s * BB + row) * XPAD + lk16 * 8;
      #pragma unroll
      for (int i = 0; i < KS_X; ++i) ldA_nc(px + i * 32, xa[i]);      // xa: 26
    }
    #pragma unroll
    for (int ks = 0; ks < 5; ++ks)
      #pragma unroll
      for (int nt = 0; nt < NTN; ++nt)
        ldA_nc(wfb + ((ks * NTN + nt) * 64 + l) * 8, xb[ks * 4 + nt]); // xb0: 46

    f32x4 acc[NTN];
    #pragma unroll
    for (int nt = 0; nt < NTN; ++nt)
      acc[nt] = (f32x4){bcol[nt], bcol[nt], bcol[nt], bcol[nt]};

    WAITV(38);  // hc0 retired (38 = xa+xb0+hc1+... younger allowed)
    #pragma unroll
    for (int i = 0; i < 8; ++i)
      #pragma unroll
      for (int nt = 0; nt < NTN; ++nt)
        acc[nt] = mfma16(ha[i], Wlds[nt][i][l], acc[nt]);
    WAITV(30);  // hc1 retired
    #pragma unroll
    for (int i = 8; i < 16; ++i)
      #pragma unroll
      for (int nt = 0; nt < NTN; ++nt)
        acc[nt] = mfma16(ha[i], Wlds[nt][i][l], acc[nt]);
    #pragma unroll
    for (int i = 16; i < 24; ++i) ldA_sc(phb + i * 2048, ha[i]);      // hc2
    WAITV(8);   // xa + xb0 retired (only hc2 may remain)
    #pragma unroll
    for (int ks = 0; ks < 5; ++ks)
      #pragma unroll
      for (int nt = 0; nt < NTN; ++nt)
        acc[nt] = mfma16(xa[ks], xb[ks * 4 + nt], acc[nt]);
    #pragma unroll
    for (int ks = 5; ks < 10; ++ks)
      #pragma unroll
      for (int nt = 0; nt < NTN; ++nt)
        ldA_nc(wfb + ((ks * NTN + nt) * 64 + l) * 8, xb[(ks - 5) * 4 + nt]); // xb1
    WAITV(20);  // hc2 retired (xb1 may fly)
    #pragma unroll
    for (int i = 16; i < 24; ++i)
      #pragma unroll
      for (int nt = 0; nt < NTN; ++nt)
        acc[nt] = mfma16(ha[i], Wlds[nt][i][l], acc[nt]);
    #pragma unroll
    for (int i = 24; i < 32; ++i) ldA_sc(phb + i * 2048, ha[i]);      // hc3
    WAITV(8);   // xb1 retired (hc3 may fly)
    #pragma unroll
    for (int ks = 5; ks < 10; ++ks)
      #pragma unroll
      for (int nt = 0; nt < NTN; ++nt)
        acc[nt] = mfma16(xa[ks], xb[(ks - 5) * 4 + nt], acc[nt]);
    WAITV(0);   // hc3 retired
    #pragma unroll
    for (int i = 24; i < 32; ++i)
      #pragma unroll
      for (int nt = 0; nt < NTN; ++nt)
        acc[nt] = mfma16(ha[i], Wlds[nt][i][l], acc[nt]);

    // ---- C exchange via LDS (C: col=lane&15, row=(lane>>4)*4+r) ----
    {
      int crow = w * 16 + (l >> 4) * 4;
      int cc = l & 15;
      #pragma unroll
      for (int nt = 0; nt < NTN; ++nt)
        #pragma unroll
        for (int r = 0; r < 4; ++r) Cs[crow + r][nt * 16 + cc] = acc[nt][r];
    }
    __syncthreads();

    // ---- pointwise + BN + pool, 4 cols per thread ----
    float h2[4], s1[4], s2[4];
    #pragma unroll
    for (int i = 0; i < 4; ++i) {
      int j = 4 * w + i;
      float gI = Cs[b][j], gF = Cs[b][16 + j];
      float gG = Cs[b][32 + j], gO = Cs[b][48 + j];
      float c2 = sigmoid_f(gF) * creg[i] + sigmoid_f(gI) * tanh_f(gG);
      h2[i] = sigmoid_f(gO) * tanh_f(c2);
      creg[i] = c2;
      s1[i] = h2[i];
      s2[i] = h2[i] * h2[i];
    }
    #pragma unroll
    for (int off = 32; off; off >>= 1)
      #pragma unroll
      for (int i = 0; i < 4; ++i) {
        s1[i] += __shfl_xor(s1[i], off, 64);
        s2[i] += __shfl_xor(s2[i], off, 64);
      }
    unsigned pk01, pk23;
    {
      float hn[4];
      #pragma unroll
      for (int i = 0; i < 4; ++i) {
        float mu = s1[i] * (1.f / 64.f);
        float var = fmaf(-mu, mu, s2[i] * (1.f / 64.f));
        hn[i] = gam[i] * (h2[i] - mu) * rsqrtf(var + BN_EPS) + bet[i];
        pool[i] = fmaxf(pool[i], hn[i] * msk[i]);
      }
      pk01 = (unsigned)tobf(h2[0]) | ((unsigned)tobf(h2[1]) << 16);
      pk23 = (unsigned)tobf(h2[2]) | ((unsigned)tobf(h2[3]) << 16);
    }
    // publish this block's 2KB segment: thread -> 8B at b*32 + w*8 (bytes)
    u32x2 pv = {pk01, pk23};
    st2_sc(hnx + (size_t)blk * 1024 + b * 16 + w * 4, pv);  // per-thread drain
    __syncthreads();  // all h data ack'd at LLC before slot raises
    if (tid == 0) st_sc32_nd(&slots[blk], (unsigned)(s + 1));  // fire-forget
  }

  // ---- per-block FC partial ----
  red_s[w][b] = pool[0] * fw[0] + pool[1] * fw[1] + pool[2] * fw[2] +
                pool[3] * fw[3];
  __syncthreads();
  if (tid < BB) {
    float part = red_s[0][tid] + red_s[1][tid] + red_s[2][tid] + red_s[3][tid];
    st_sc32(&partial[(size_t)tid * NBLK + blk], __float_as_uint(part));
  }
  __syncthreads();
  if (tid == 0) st_sc32_nd(&slots[blk], (unsigned)(TT + 2));
  if (blk != 0) return;

  // ---- block 0: final reduction + loss ----
  poll_ge(slots, tid, (unsigned)(TT + 2));
  {
    int fb = tid & 63, q = tid >> 6;
    const float* pp = partial + ((size_t)fb * NBLK + q * 16);
    f32x4 v0, v1, v2, v3;
    ld4_sc(pp + 0, v0); ld4_sc(pp + 4, v1);
    ld4_sc(pp + 8, v2); ld4_sc(pp + 12, v3);
    WAITV(0);
    red_s[q][fb] = v0.x + v0.y + v0.z + v0.w + v1.x + v1.y + v1.z + v1.w +
                   v2.x + v2.y + v2.z + v2.w + v3.x + v3.y + v3.z + v3.w;
  }
  __syncthreads();
  if (tid < BB) {
    float z = red_s[0][tid] + red_s[1][tid] + red_s[2][tid] + red_s[3][tid] + fcb[0];
    outp[1 + tid] = z;
    float sp = fmaxf(z, 0.f) + log1pf(__expf(-fabsf(z)));
    float lt = sp - z * tlbl[tid];
#pragma unroll
    for (int off = 32; off; off >>= 1) lt += __shfl_xor(lt, off, 64);
    if (tid == 0) outp[0] = lt * (1.f / 64.f);
  }
}

extern "C" void kernel_launch(void* const* d_in, const int* in_sizes, int n_in,
                              void* d_out, int out_size, void* d_ws, size_t ws_size,
                              hipStream_t stream) {
  const float* x = (const float*)d_in[0];
  const float* tlbl = (const float*)d_in[1];
  const float* maskp = (const float*)d_in[2];
  const float* Wih = (const float*)d_in[3];
  const float* Whh = (const float*)d_in[4];
  const float* bih = (const float*)d_in[5];
  const float* bhh = (const float*)d_in[6];
  const float* gammap = (const float*)d_in[7];
  const float* betap = (const float*)d_in[8];
  const float* fcw = (const float*)d_in[9];
  const float* fcb = (const float*)d_in[10];
  float* outp = (float*)d_out;

  // ws: slots(256B)+pad @0 | hbuf 2x128KB @4KB | partial 16KB | wfrag 2.56MB
  //     | xbf 20.97MB  (total ~23.9 MB)
  unsigned* slots = (unsigned*)d_ws;
  unsigned short* hbuf = (unsigned short*)((char*)d_ws + 4096);
  float* partial = (float*)((char*)d_ws + 4096 + 2 * BB * HH * 2);
  unsigned short* wfrag =
      (unsigned short*)((char*)d_ws + 4096 + 2 * BB * HH * 2 + BB * NBLK * 4);
  unsigned short* xbf = wfrag + (size_t)NBLK * KS_X * NTN * 64 * 8;

  // zero slots + h image 0 (contiguous from ws base: 4096B + 128KB)
  int ndw = (4096 + BB * HH * 2) / 4;
  hipLaunchKernelGGL(init_k, dim3(64), dim3(NTH), 0, stream, (unsigned*)d_ws, ndw);
  hipLaunchKernelGGL(xcvt_k, dim3(2048), dim3(NTH), 0, stream, x, xbf);
  hipLaunchKernelGGL(wihfrag_k, dim3(640), dim3(NTH), 0, stream, Wih, wfrag);
  hipLaunchKernelGGL(lstm_mfma, dim3(NBLK), dim3(NTH), 0, stream,
                     Whh, bih, bhh, gammap, betap, maskp, tlbl, fcw, fcb,
                     xbf, wfrag, hbuf, partial, slots, outp);
}

// Round 9
// 5212.885 us; speedup vs baseline: 1.0786x; 1.0786x over previous
//
#include <hip/hip_runtime.h>
#include <cstddef>
#include <cstdint>

#define BB 64
#define TT 512
#define HH 1024
#define DD 300
#define NTH 256
#define NBLK 128
#define JB 8            // h-indices per block (NBLK*JB == HH)
#define GB 16           // samples per group; wave w <-> group g
#define XPAD 320
#define KS_X 10
#define KS_H 32
#define KS_T 42
#define BN_EPS 1e-5f

typedef short short8 __attribute__((ext_vector_type(8)));
typedef float f32x4 __attribute__((ext_vector_type(4)));
typedef unsigned u32x2 __attribute__((ext_vector_type(2)));
typedef unsigned u32x4 __attribute__((ext_vector_type(4)));

__device__ __forceinline__ float sigmoid_f(float v) {
  v = fminf(fmaxf(v, -30.f), 30.f);
  return 1.f / (1.f + __expf(-v));
}
__device__ __forceinline__ float tanh_f(float v) {
  float e = __expf(fminf(fmaxf(2.f * v, -30.f), 30.f));
  return (e - 1.f) / (e + 1.f);
}
__device__ __forceinline__ unsigned short tobf(float f) {
  unsigned u = __float_as_uint(f);
  u += 0x7fffu + ((u >> 16) & 1u);
  return (unsigned short)(u >> 16);
}
__device__ __forceinline__ float bf2f(unsigned us) {  // us = 16-bit bf16
  return __uint_as_float(us << 16);
}

// ---- inline-asm vmem (exact vmcnt ledger; in-order retirement) ----
__device__ __forceinline__ void ldA_sc(const void* p, short8& d) {
  asm volatile("global_load_dwordx4 %0, %1, off sc0 sc1"
               : "=v"(d) : "v"(p) : "memory");
}
__device__ __forceinline__ void ldA_nc(const void* p, short8& d) {
  asm volatile("global_load_dwordx4 %0, %1, off"
               : "=v"(d) : "v"(p) : "memory");
}
__device__ __forceinline__ void ld2w_sc_nd(const void* p, u32x2& d) {
  asm volatile("global_load_dwordx2 %0, %1, off sc0 sc1"
               : "=v"(d) : "v"(p) : "memory");
}
__device__ __forceinline__ u32x2 ld2w_sc(const void* p) {  // drained
  u32x2 v;
  asm volatile("global_load_dwordx2 %0, %1, off sc0 sc1\n\ts_waitcnt vmcnt(0)"
               : "=v"(v) : "v"(p) : "memory");
  return v;
}
__device__ __forceinline__ void st_sc32(void* p, unsigned v) {  // drained
  asm volatile("global_store_dword %0, %1, off sc0 sc1\n\ts_waitcnt vmcnt(0)"
               :: "v"(p), "v"(v) : "memory");
}
__device__ __forceinline__ void st_sc32_nd(void* p, unsigned v) {
  asm volatile("global_store_dword %0, %1, off sc0 sc1"
               :: "v"(p), "v"(v) : "memory");
}
__device__ __forceinline__ void st4_sc_nd(void* p, u32x4 v) {
  asm volatile("global_store_dwordx4 %0, %1, off sc0 sc1"
               :: "v"(p), "v"(v) : "memory");
}
#define WAITV(N)                                                   \
  do {                                                             \
    asm volatile("s_waitcnt vmcnt(" #N ")" ::: "memory");          \
    __builtin_amdgcn_sched_barrier(0);                             \
  } while (0)

__device__ __forceinline__ f32x4 mfma16(short8 a, short8 b, f32x4 c) {
  return __builtin_amdgcn_mfma_f32_16x16x32_bf16(a, b, c, 0, 0, 0);
}

// per-wave poll of 128 slots (drained probes; used as slow path / phase2 gate)
__device__ __forceinline__ void poll128(const unsigned* sl, int l, unsigned ep) {
  int it = 0;
  for (;;) {
    u32x2 v = ld2w_sc(&sl[2 * l]);
    if (__all((v.x >= ep) && (v.y >= ep))) break;
    if (++it > (1 << 20)) break;  // valve: fail visibly, never hang
    if (it > 2) __builtin_amdgcn_s_sleep(1);
  }
}

__global__ void init_k(unsigned* __restrict__ slots) {
  int idx = blockIdx.x * blockDim.x + threadIdx.x;
  if (idx < 4 * NBLK) st_sc32(&slots[idx], 0u);
}

// x [b][t][d] f32 -> xbf [t][b][XPAD] bf16 (zero-padded)
__global__ void xcvt_k(const float* __restrict__ x, unsigned short* __restrict__ xbf) {
  const int total = TT * BB * XPAD;
  for (int idx = blockIdx.x * blockDim.x + threadIdx.x; idx < total;
       idx += gridDim.x * blockDim.x) {
    int kx = idx % XPAD;
    int tb = idx / XPAD;
    int b = tb % BB, t = tb / BB;
    float v = (kx < DD) ? x[(size_t)b * (TT * DD) + (size_t)t * DD + kx] : 0.f;
    xbf[idx] = tobf(v);
  }
}

// ---------- phase 1: 4 decoupled per-group LSTM chains per block ----------
__global__ void __launch_bounds__(NTH, 1)
lstm_k(const float* __restrict__ Wih, const float* __restrict__ Whh,
       const float* __restrict__ bih, const float* __restrict__ bhh,
       const unsigned short* __restrict__ xbf, unsigned short* __restrict__ hall,
       unsigned* __restrict__ slots) {
  // B-frags: Wlds[nt][ks][lane] = 8 bf16 of B[k=ks*32+(lane>>4)*8+e][col],
  // col = nt*16 + (lane&15); gate = col>>3, j = col&7 (block cols = 8 h-idx x
  // 4 gates). ks<32: W_hh (k = h-index); ks>=32: W_ih (zero-padded).
  __shared__ short8 Wlds[2][KS_T][64];      // 86 KB
  __shared__ unsigned short rep[4][GB][JB]; // 1 KB per-wave repack

  const int tid = threadIdx.x;
  const int g = tid >> 6, l = tid & 63;
  const int blk = blockIdx.x, jb0 = blk * JB;

  for (int idx = tid; idx < 2 * KS_T * 64; idx += NTH) {
    int nt = idx / (KS_T * 64);
    int rem = idx % (KS_T * 64);
    int ks = rem >> 6, ll = rem & 63;
    int c = nt * 16 + (ll & 15);
    int r = (c >> 3) * HH + jb0 + (c & 7);
    int k0 = (ll >> 4) * 8;
    short8 pk;
    if (ks < KS_H) {
      const float* src = Whh + (size_t)r * HH + ks * 32 + k0;
      f32x4 u0 = *(const f32x4*)src;
      f32x4 u1 = *(const f32x4*)(src + 4);
      pk[0] = (short)tobf(u0.x); pk[1] = (short)tobf(u0.y);
      pk[2] = (short)tobf(u0.z); pk[3] = (short)tobf(u0.w);
      pk[4] = (short)tobf(u1.x); pk[5] = (short)tobf(u1.y);
      pk[6] = (short)tobf(u1.z); pk[7] = (short)tobf(u1.w);
    } else {
      int d0 = (ks - KS_H) * 32 + k0;
#pragma unroll
      for (int e = 0; e < 8; ++e)
        pk[e] = (d0 + e < DD) ? (short)tobf(Wih[(size_t)r * DD + d0 + e]) : (short)0;
    }
    Wlds[nt][ks][ll] = pk;
  }

  const int cq = l & 15;
  const float bc0 = bih[(cq >> 3) * HH + jb0 + (cq & 7)] +
                    bhh[(cq >> 3) * HH + jb0 + (cq & 7)];
  const float bc1 = bih[((cq >> 3) + 2) * HH + jb0 + (cq & 7)] +
                    bhh[((cq >> 3) + 2) * HH + jb0 + (cq & 7)];
  const int arow = g * GB + (l & 15);  // global sample for A-frags (M row)
  const int lk16 = l >> 4;
  const unsigned* slg = slots + g * NBLK;
  unsigned* slg_w = slots + g * NBLK;

  // pointwise role (from C layout col=lane&15, row=(lane>>4)*4+reg):
  // low lane (cq<8): rows 4q+0,1 (regs 0,1), j=cq; high: rows 4q+2,3, j=cq-8.
  const int low = (cq < 8) ? 1 : 0;
  const int jj = low ? cq : cq - 8;
  const int sl0 = (l >> 4) * 4 + (low ? 0 : 2);
  float cr0 = 0.f, cr1 = 0.f;
  __syncthreads();  // Wlds visible; no block barrier after this point

  for (int s = 0; s < TT; ++s) {
    // ---- probe (overlapped with x-loads) + x issue ----
    const unsigned short* px = xbf + ((size_t)s * BB + arow) * XPAD + lk16 * 8;
    short8 xa[KS_X];
    if (s > 0) {
      u32x2 pv;
      ld2w_sc_nd(&slg[2 * l], pv);  // probe FIRST (oldest in queue)
#pragma unroll
      for (int i = 0; i < KS_X; ++i) ldA_nc(px + i * 32, xa[i]);
      WAITV(10);  // probe retired; x still in flight
      if (!__all((pv.x >= (unsigned)s) && (pv.y >= (unsigned)s)))
        poll128(slg, l, (unsigned)s);  // slow path (drains x; we're stalled anyway)
    } else {
#pragma unroll
      for (int i = 0; i < KS_X; ++i) ldA_nc(px + i * 32, xa[i]);
      WAITV(0);
    }

    short8 ha[KS_H];
    if (s > 0) {
      const unsigned short* ph =
          hall + ((size_t)(s - 1) * BB + arow) * HH + lk16 * 8;
#pragma unroll
      for (int i = 0; i < KS_H; ++i) ldA_sc(ph + i * 32, ha[i]);
      WAITV(32);  // x fully retired; exactly the 32 h-loads outstanding
    }

    f32x4 acc0 = {bc0, bc0, bc0, bc0}, acc1 = {bc1, bc1, bc1, bc1};
#pragma unroll
    for (int i = 0; i < KS_X; ++i) {  // x-MFMAs hide h chunk0 latency
      acc0 = mfma16(xa[i], Wlds[0][KS_H + i][l], acc0);
      acc1 = mfma16(xa[i], Wlds[1][KS_H + i][l], acc1);
    }
    if (s > 0) {
      WAITV(24);
#pragma unroll
      for (int i = 0; i < 8; ++i) {
        acc0 = mfma16(ha[i], Wlds[0][i][l], acc0);
        acc1 = mfma16(ha[i], Wlds[1][i][l], acc1);
      }
      WAITV(16);
#pragma unroll
      for (int i = 8; i < 16; ++i) {
        acc0 = mfma16(ha[i], Wlds[0][i][l], acc0);
        acc1 = mfma16(ha[i], Wlds[1][i][l], acc1);
      }
      WAITV(8);
#pragma unroll
      for (int i = 16; i < 24; ++i) {
        acc0 = mfma16(ha[i], Wlds[0][i][l], acc0);
        acc1 = mfma16(ha[i], Wlds[1][i][l], acc1);
      }
      WAITV(0);
#pragma unroll
      for (int i = 24; i < 32; ++i) {
        acc0 = mfma16(ha[i], Wlds[0][i][l], acc0);
        acc1 = mfma16(ha[i], Wlds[1][i][l], acc1);
      }
    }

    // ---- in-wave pointwise (no BN here): xor-8 gate exchange ----
    f32x4 o0, o1;
#pragma unroll
    for (int r = 0; r < 4; ++r) {
      o0[r] = __shfl_xor(acc0[r], 8, 64);
      o1[r] = __shfl_xor(acc1[r], 8, 64);
    }
    {
      int r0 = low ? 0 : 2, r1 = r0 + 1;
      float gi0 = low ? acc0[r0] : o0[r0];
      float gf0 = low ? o0[r0] : acc0[r0];
      float gg0 = low ? acc1[r0] : o1[r0];
      float go0 = low ? o1[r0] : acc1[r0];
      float gi1 = low ? acc0[r1] : o0[r1];
      float gf1 = low ? o0[r1] : acc0[r1];
      float gg1 = low ? acc1[r1] : o1[r1];
      float go1 = low ? o1[r1] : acc1[r1];
      float c20 = sigmoid_f(gf0) * cr0 + sigmoid_f(gi0) * tanh_f(gg0);
      float h20 = sigmoid_f(go0) * tanh_f(c20);
      float c21 = sigmoid_f(gf1) * cr1 + sigmoid_f(gi1) * tanh_f(gg1);
      float h21 = sigmoid_f(go1) * tanh_f(c21);
      cr0 = c20;
      cr1 = c21;
      rep[g][sl0][jj] = tobf(h20);
      rep[g][sl0 + 1][jj] = tobf(h21);
    }
    asm volatile("s_waitcnt lgkmcnt(0)" ::: "memory");
    __builtin_amdgcn_sched_barrier(0);

    // ---- publish 16 rows x 16B (full lines), drain, fire-forget slot ----
    if (l < GB) {
      u32x4 pv = *(const u32x4*)&rep[g][l][0];
      st4_sc_nd(hall + ((size_t)s * BB + g * GB + l) * HH + jb0, pv);
    }
    WAITV(0);
    if (l == 0) st_sc32_nd(&slg_w[blk], (unsigned)(s + 1));
  }
}

// ---------- phase 2a: per-(s,j) BN stats over batch ----------
__global__ void __launch_bounds__(NTH, 4)
stats_k(const unsigned short* __restrict__ hall, float* __restrict__ musig) {
  int s = blockIdx.x, tid = threadIdx.x;
  const unsigned short* base = hall + (size_t)s * BB * HH + tid * 4;
  float sm0 = 0, sm1 = 0, sm2 = 0, sm3 = 0, q0 = 0, q1 = 0, q2 = 0, q3 = 0;
  u32x2 v[8];
  for (int b0 = 0; b0 < BB; b0 += 8) {
#pragma unroll
    for (int i = 0; i < 8; ++i) ld2w_sc_nd(base + (size_t)(b0 + i) * HH, v[i]);
    WAITV(0);
#pragma unroll
    for (int i = 0; i < 8; ++i) {
      float f0 = bf2f(v[i].x & 0xffffu), f1 = bf2f(v[i].x >> 16);
      float f2 = bf2f(v[i].y & 0xffffu), f3 = bf2f(v[i].y >> 16);
      sm0 += f0; q0 += f0 * f0;
      sm1 += f1; q1 += f1 * f1;
      sm2 += f2; q2 += f2 * f2;
      sm3 += f3; q3 += f3 * f3;
    }
  }
  float mu0 = sm0 * (1.f / 64.f), mu1 = sm1 * (1.f / 64.f);
  float mu2 = sm2 * (1.f / 64.f), mu3 = sm3 * (1.f / 64.f);
  f32x4 a = {mu0, rsqrtf(fmaf(-mu0, mu0, q0 * (1.f / 64.f)) + BN_EPS),
             mu1, rsqrtf(fmaf(-mu1, mu1, q1 * (1.f / 64.f)) + BN_EPS)};
  f32x4 b = {mu2, rsqrtf(fmaf(-mu2, mu2, q2 * (1.f / 64.f)) + BN_EPS),
             mu3, rsqrtf(fmaf(-mu3, mu3, q3 * (1.f / 64.f)) + BN_EPS)};
  float* o = musig + ((size_t)s * HH + tid * 4) * 2;
  *(f32x4*)o = a;
  *(f32x4*)(o + 4) = b;
}

// ---------- phase 2b: BN apply + mask + maxpool over T + FC partial ----------
__global__ void __launch_bounds__(NTH, 4)
pool_k(const unsigned short* __restrict__ hall, const float* __restrict__ musig,
       const float* __restrict__ gammap, const float* __restrict__ betap,
       const float* __restrict__ maskp, const float* __restrict__ fcw,
       const float* __restrict__ fcb, float* __restrict__ outp,
       float* __restrict__ zbuf) {
  __shared__ float red[4][64];
  int b = blockIdx.x, tid = threadIdx.x;
  int j0 = tid * 4;
  float gm[4], bt[4], mk[4], fwv[4], pool[4];
#pragma unroll
  for (int i = 0; i < 4; ++i) {
    gm[i] = gammap[j0 + i];
    bt[i] = betap[j0 + i];
    mk[i] = maskp[(size_t)b * HH + j0 + i];
    fwv[i] = fcw[j0 + i];
    pool[i] = -3.4e38f;
  }
  const unsigned short* hb = hall + (size_t)b * HH + j0;
  u32x2 hv[8];
  for (int s0 = 0; s0 < TT; s0 += 8) {
#pragma unroll
    for (int i = 0; i < 8; ++i)
      ld2w_sc_nd(hb + (size_t)(s0 + i) * (BB * HH), hv[i]);
    WAITV(0);
#pragma unroll
    for (int i = 0; i < 8; ++i) {
      const float* ms = musig + ((size_t)(s0 + i) * HH + j0) * 2;
      f32x4 m0 = *(const f32x4*)ms;
      f32x4 m1 = *(const f32x4*)(ms + 4);
      float f0 = bf2f(hv[i].x & 0xffffu), f1 = bf2f(hv[i].x >> 16);
      float f2 = bf2f(hv[i].y & 0xffffu), f3 = bf2f(hv[i].y >> 16);
      pool[0] = fmaxf(pool[0], (gm[0] * (f0 - m0.x) * m0.y + bt[0]) * mk[0]);
      pool[1] = fmaxf(pool[1], (gm[1] * (f1 - m0.z) * m0.w + bt[1]) * mk[1]);
      pool[2] = fmaxf(pool[2], (gm[2] * (f2 - m1.x) * m1.y + bt[2]) * mk[2]);
      pool[3] = fmaxf(pool[3], (gm[3] * (f3 - m1.z) * m1.w + bt[3]) * mk[3]);
    }
  }
  float part = pool[0] * fwv[0] + pool[1] * fwv[1] + pool[2] * fwv[2] +
               pool[3] * fwv[3];
  red[tid >> 6][tid & 63] = part;
  __syncthreads();
  if (tid < 64) {
    float v = red[0][tid] + red[1][tid] + red[2][tid] + red[3][tid];
#pragma unroll
    for (int off = 32; off; off >>= 1) v += __shfl_xor(v, off, 64);
    if (tid == 0) {
      float z = v + fcb[0];
      outp[1 + b] = z;
      zbuf[b] = z;
    }
  }
}

// ---------- phase 2c: BCE loss ----------
__global__ void loss_k(const float* __restrict__ zbuf,
                       const float* __restrict__ tlbl, float* __restrict__ outp) {
  int tid = threadIdx.x;  // 64 threads
  float z = zbuf[tid];
  float sp = fmaxf(z, 0.f) + log1pf(__expf(-fabsf(z)));
  float lt = sp - z * tlbl[tid];
#pragma unroll
  for (int off = 32; off; off >>= 1) lt += __shfl_xor(lt, off, 64);
  if (tid == 0) outp[0] = lt * (1.f / 64.f);
}

extern "C" void kernel_launch(void* const* d_in, const int* in_sizes, int n_in,
                              void* d_out, int out_size, void* d_ws, size_t ws_size,
                              hipStream_t stream) {
  const float* x = (const float*)d_in[0];
  const float* tlbl = (const float*)d_in[1];
  const float* maskp = (const float*)d_in[2];
  const float* Wih = (const float*)d_in[3];
  const float* Whh = (const float*)d_in[4];
  const float* bih = (const float*)d_in[5];
  const float* bhh = (const float*)d_in[6];
  const float* gammap = (const float*)d_in[7];
  const float* betap = (const float*)d_in[8];
  const float* fcw = (const float*)d_in[9];
  const float* fcb = (const float*)d_in[10];
  float* outp = (float*)d_out;

  // ws: slots 2KB @0 | zbuf @2560 | hall 64MB @64KB | musig 4MB | xbf 20MB
  // total ~92.4 MB
  unsigned* slots = (unsigned*)d_ws;
  float* zbuf = (float*)((char*)d_ws + 2560);
  unsigned short* hall = (unsigned short*)((char*)d_ws + 65536);
  float* musig = (float*)((char*)d_ws + 65536 + (size_t)TT * BB * HH * 2);
  unsigned short* xbf =
      (unsigned short*)((char*)musig + (size_t)TT * HH * 2 * sizeof(float));

  hipLaunchKernelGGL(init_k, dim3(2), dim3(NTH), 0, stream, slots);
  hipLaunchKernelGGL(xcvt_k, dim3(2048), dim3(NTH), 0, stream, x, xbf);
  hipLaunchKernelGGL(lstm_k, dim3(NBLK), dim3(NTH), 0, stream,
                     Wih, Whh, bih, bhh, xbf, hall, slots);
  hipLaunchKernelGGL(stats_k, dim3(TT), dim3(NTH), 0, stream, hall, musig);
  hipLaunchKernelGGL(pool_k, dim3(BB), dim3(NTH), 0, stream,
                     hall, musig, gammap, betap, maskp, fcw, fcb, outp, zbuf);
  hipLaunchKernelGGL(loss_k, dim3(1), dim3(64), 0, stream, zbuf, tlbl, outp);
}

// Round 12
// 3860.036 us; speedup vs baseline: 1.4566x; 1.3505x over previous
//
#include <hip/hip_runtime.h>
#include <cstddef>
#include <cstdint>

#define BB 64
#define TT 512
#define HH 1024
#define DD 300
#define NTH 256
#define NBLK 128
#define HB 8                  // h-indices per block
#define XPAD 320              // x K padded to 10*32
#define KS_X 10
#define KS_H 32
#define BN_EPS 1e-5f

typedef short short8 __attribute__((ext_vector_type(8)));
typedef float f32x4 __attribute__((ext_vector_type(4)));
typedef unsigned u32x2 __attribute__((ext_vector_type(2)));
typedef unsigned u32x4 __attribute__((ext_vector_type(4)));

__device__ __forceinline__ float sigmoid_f(float v) {
  v = fminf(fmaxf(v, -30.f), 30.f);
  return 1.f / (1.f + __expf(-v));
}
__device__ __forceinline__ float tanh_f(float v) {
  float e = __expf(fminf(fmaxf(2.f * v, -30.f), 30.f));
  return (e - 1.f) / (e + 1.f);
}
__device__ __forceinline__ unsigned short tobf(float f) {
  unsigned u = __float_as_uint(f);
  u += 0x7fffu + ((u >> 16) & 1u);
  return (unsigned short)(u >> 16);
}

// ---- all in-loop vmem is inline asm so counted-vmcnt bookkeeping stays exact
__device__ __forceinline__ void ldA_sc(const void* p, short8& d) {
  asm volatile("global_load_dwordx4 %0, %1, off sc0 sc1"
               : "=v"(d) : "v"(p) : "memory");
}
__device__ __forceinline__ void ldA_nc(const void* p, short8& d) {
  asm volatile("global_load_dwordx4 %0, %1, off"
               : "=v"(d) : "v"(p) : "memory");
}
__device__ __forceinline__ void ld4_sc(const void* p, f32x4& d) {
  asm volatile("global_load_dwordx4 %0, %1, off sc0 sc1"
               : "=v"(d) : "v"(p) : "memory");
}
__device__ __forceinline__ u32x2 ld2w_sc(const void* p) {
  u32x2 v;
  asm volatile("global_load_dwordx2 %0, %1, off sc0 sc1\n\ts_waitcnt vmcnt(0)"
               : "=v"(v) : "v"(p) : "memory");
  return v;
}
__device__ __forceinline__ void st_sc32(void* p, unsigned v) {  // with drain
  asm volatile("global_store_dword %0, %1, off sc0 sc1\n\ts_waitcnt vmcnt(0)"
               :: "v"(p), "v"(v) : "memory");
}
__device__ __forceinline__ void st_sc32_nd(void* p, unsigned v) {  // no drain
  asm volatile("global_store_dword %0, %1, off sc0 sc1"
               :: "v"(p), "v"(v) : "memory");
}
__device__ __forceinline__ void st4_sc_nd(void* p, u32x4 v) {  // no drain
  asm volatile("global_store_dwordx4 %0, %1, off sc0 sc1"
               :: "v"(p), "v"(v) : "memory");
}
#define WAITV(N)                                                   \
  do {                                                             \
    asm volatile("s_waitcnt vmcnt(" #N ")" ::: "memory");          \
    __builtin_amdgcn_sched_barrier(0);                             \
  } while (0)

__device__ __forceinline__ f32x4 mfma16(short8 a, short8 b, f32x4 c) {
  return __builtin_amdgcn_mfma_f32_16x16x32_bf16(a, b, c, 0, 0, 0);
}

// wave0-only poll: lane i checks slots[2i], slots[2i+1]. Drained probes.
// NOTE: wave0's first probe also drains wave0's in-flight x-prefetch — that
// cost is hidden inside the wait-for-producers window (we are stalled anyway).
__device__ __forceinline__ void poll_ge(const unsigned* slots, int tid, unsigned ep) {
  int it = 0;
  for (;;) {
    int ok = 1;
    if (tid < 64) {
      u32x2 v = ld2w_sc(&slots[2 * tid]);
      ok = (v.x >= ep && v.y >= ep) ? 1 : 0;
    }
    if (__syncthreads_and(ok)) break;
    if (++it > (1 << 20)) break;  // valve: fail visibly, never hang
    if (it > 2) __builtin_amdgcn_s_sleep(1);
  }
}

__global__ void init_k(unsigned* __restrict__ base, int ndw) {
  int idx = blockIdx.x * blockDim.x + threadIdx.x;
  for (int i = idx; i < ndw; i += gridDim.x * blockDim.x) st_sc32(base + i, 0u);
}

// x [b][t][d] f32 -> xbf [t][b][XPAD] bf16 (zero-padded)
__global__ void xcvt_k(const float* __restrict__ x, unsigned short* __restrict__ xbf) {
  const int total = TT * BB * XPAD;
  for (int idx = blockIdx.x * blockDim.x + threadIdx.x; idx < total;
       idx += gridDim.x * blockDim.x) {
    int kx = idx % XPAD;
    int tb = idx / XPAD;
    int b = tb % BB, t = tb / BB;
    float v = (kx < DD) ? x[(size_t)b * (TT * DD) + (size_t)t * DD + kx] : 0.f;
    xbf[idx] = tobf(v);
  }
}

__global__ void __launch_bounds__(NTH, 1)
lstm_mfma(const float* __restrict__ Wih, const float* __restrict__ Whh,
          const float* __restrict__ bih, const float* __restrict__ bhh,
          const float* __restrict__ gammap, const float* __restrict__ betap,
          const float* __restrict__ maskp, const float* __restrict__ tlbl,
          const float* __restrict__ fcw, const float* __restrict__ fcb,
          const unsigned short* __restrict__ xbf, unsigned short* __restrict__ hbuf,
          float* __restrict__ partial, unsigned* __restrict__ slots,
          float* __restrict__ outp) {
  // B-operand fragments: Wlds[nt][ks][lane] = 8 bf16 of
  // B[k = ks*32 + (lane>>4)*8 + e][col = nt*16 + (lane&15)].
  // ks 0..31 = W_hh, 32..41 = W_ih (zero-padded). Lane-linear ds_read_b128.
  __shared__ short8 Wlds[2][KS_H + KS_X][64];  // 84 KB
  __shared__ float Cs[64][33];                 // 8.4 KB (+1 pad)
  __shared__ unsigned pkbuf[BB][4];            // 1 KB staged publish
  __shared__ float red_s[4][64];               // 1 KB

  const int tid = threadIdx.x;
  const int w = tid >> 6, l = tid & 63;
  const int blk = blockIdx.x;
  const int hb0 = blk * HB;

  // ---- stage W as bf16 fragments (once) ----
  for (int idx = tid; idx < 2 * (KS_H + KS_X) * 64; idx += NTH) {
    int nt = idx / ((KS_H + KS_X) * 64);
    int rem = idx % ((KS_H + KS_X) * 64);
    int ks = rem >> 6, ll = rem & 63;
    int colq = nt * 16 + (ll & 15);
    int g = colq >> 3, j = colq & 7;
    int r = g * HH + hb0 + j;
    int k0 = (ll >> 4) * 8;
    float v[8];
    if (ks < KS_H) {
      const float* src = Whh + (size_t)r * HH + ks * 32 + k0;
      f32x4 u0 = *(const f32x4*)src;
      f32x4 u1 = *(const f32x4*)(src + 4);
      v[0] = u0.x; v[1] = u0.y; v[2] = u0.z; v[3] = u0.w;
      v[4] = u1.x; v[5] = u1.y; v[6] = u1.z; v[7] = u1.w;
    } else {
      int d0 = (ks - KS_H) * 32 + k0;
#pragma unroll
      for (int e = 0; e < 8; ++e)
        v[e] = (d0 + e < DD) ? Wih[(size_t)r * DD + d0 + e] : 0.f;
    }
    short8 pk;
#pragma unroll
    for (int e = 0; e < 8; ++e) pk[e] = (short)tobf(v[e]);
    Wlds[nt][ks][ll] = pk;
  }

  // ---- MFMA roles: wave = M-tile; computes both N-tiles ----
  const int row = w * 16 + (l & 15);
  const int lk16 = (l >> 4);

  // per-column combined bias (folded into acc init)
  const int cq = l & 15;
  const float bcol0 = bih[(cq >> 3) * HH + hb0 + (cq & 7)] +
                      bhh[(cq >> 3) * HH + hb0 + (cq & 7)];
  const float bcol1 = bih[(2 + (cq >> 3)) * HH + hb0 + (cq & 7)] +
                      bhh[(2 + (cq >> 3)) * HH + hb0 + (cq & 7)];

  // ---- pointwise roles: lane = batch, wave w -> h-sub j0=2w, j1=2w+1 ----
  const int b = l, j0 = 2 * w, j1 = 2 * w + 1;
  const float gam0 = gammap[hb0 + j0], gam1 = gammap[hb0 + j1];
  const float bet0 = betap[hb0 + j0], bet1 = betap[hb0 + j1];
  const float msk0 = maskp[(size_t)b * HH + hb0 + j0];
  const float msk1 = maskp[(size_t)b * HH + hb0 + j1];
  const float fw0 = fcw[hb0 + j0], fw1 = fcw[hb0 + j1];
  float creg0 = 0.f, creg1 = 0.f;
  float pool0 = -3.4e38f, pool1 = -3.4e38f;

  // prologue: issue x-loads for s=0
  short8 xa[KS_X];
  {
    const unsigned short* px = xbf + ((size_t)0 * BB + row) * XPAD + lk16 * 8;
#pragma unroll
    for (int i = 0; i < KS_X; ++i) ldA_nc(px + i * 32, xa[i]);
  }
  __syncthreads();  // Wlds visible

  for (int s = 0; s < TT; ++s) {
    const unsigned short* hc = hbuf + (size_t)(s & 1) * (BB * HH);
    unsigned short* hnx = hbuf + (size_t)((s + 1) & 1) * (BB * HH);

    // wait for h_s publication (s=0 passes immediately)
    poll_ge(slots, tid, (unsigned)s);

    // issue ALL 32 h A-frag loads (addr = hc + (ks*4 + lk16)*512 + row*8)
    const unsigned short* ph = hc + (size_t)lk16 * 512 + row * 8;
    short8 ha[KS_H];
#pragma unroll
    for (int i = 0; i < KS_H; ++i) ldA_sc(ph + i * 2048, ha[i]);

    // drain everything except the 32 h-loads. Per-wave queues here:
    // w0 = [h32] (x drained by its poll probe), w1/w3 = [x10,h32] = 42,
    // w2 = [slot,x10,h32] = 43 -> WAITV(32) lands every wave at exactly 32.
    WAITV(32);

    // x-MFMAs while h chunk0 is in flight; 4 independent acc chains
    f32x4 acc0a = {bcol0, bcol0, bcol0, bcol0}, acc0b = {0.f, 0.f, 0.f, 0.f};
    f32x4 acc1a = {bcol1, bcol1, bcol1, bcol1}, acc1b = {0.f, 0.f, 0.f, 0.f};
#pragma unroll
    for (int i = 0; i < KS_X; i += 2) {
      acc0a = mfma16(xa[i], Wlds[0][KS_H + i][l], acc0a);
      acc1a = mfma16(xa[i], Wlds[1][KS_H + i][l], acc1a);
      acc0b = mfma16(xa[i + 1], Wlds[0][KS_H + i + 1][l], acc0b);
      acc1b = mfma16(xa[i + 1], Wlds[1][KS_H + i + 1][l], acc1b);
    }
    WAITV(24);  // h chunk0 (loads 0..7) done
#pragma unroll
    for (int i = 0; i < 8; i += 2) {
      acc0a = mfma16(ha[i], Wlds[0][i][l], acc0a);
      acc1a = mfma16(ha[i], Wlds[1][i][l], acc1a);
      acc0b = mfma16(ha[i + 1], Wlds[0][i + 1][l], acc0b);
      acc1b = mfma16(ha[i + 1], Wlds[1][i + 1][l], acc1b);
    }
    WAITV(16);  // chunk1
#pragma unroll
    for (int i = 8; i < 16; i += 2) {
      acc0a = mfma16(ha[i], Wlds[0][i][l], acc0a);
      acc1a = mfma16(ha[i], Wlds[1][i][l], acc1a);
      acc0b = mfma16(ha[i + 1], Wlds[0][i + 1][l], acc0b);
      acc1b = mfma16(ha[i + 1], Wlds[1][i + 1][l], acc1b);
    }
    WAITV(8);  // chunk2
#pragma unroll
    for (int i = 16; i < 24; i += 2) {
      acc0a = mfma16(ha[i], Wlds[0][i][l], acc0a);
      acc1a = mfma16(ha[i], Wlds[1][i][l], acc1a);
      acc0b = mfma16(ha[i + 1], Wlds[0][i + 1][l], acc0b);
      acc1b = mfma16(ha[i + 1], Wlds[1][i + 1][l], acc1b);
    }
    WAITV(0);  // chunk3
#pragma unroll
    for (int i = 24; i < 32; i += 2) {
      acc0a = mfma16(ha[i], Wlds[0][i][l], acc0a);
      acc1a = mfma16(ha[i], Wlds[1][i][l], acc1a);
      acc0b = mfma16(ha[i + 1], Wlds[0][i + 1][l], acc0b);
      acc1b = mfma16(ha[i + 1], Wlds[1][i + 1][l], acc1b);
    }
    f32x4 acc0 = acc0a + acc0b, acc1 = acc1a + acc1b;

    // ---- C exchange via LDS (C: col=lane&15, row=(lane>>4)*4+r) ----
    {
      int crow = w * 16 + (l >> 4) * 4;
      int cc0 = (l & 15), cc1 = 16 + (l & 15);
#pragma unroll
      for (int r = 0; r < 4; ++r) {
        Cs[crow + r][cc0] = acc0[r];
        Cs[crow + r][cc1] = acc1[r];
      }
    }
    __syncthreads();

    // ---- pointwise + BN + pool (gates already include bias) ----
    float gI0 = Cs[b][j0],      gF0 = Cs[b][8 + j0];
    float gG0 = Cs[b][16 + j0], gO0 = Cs[b][24 + j0];
    float gI1 = Cs[b][j1],      gF1 = Cs[b][8 + j1];
    float gG1 = Cs[b][16 + j1], gO1 = Cs[b][24 + j1];
    float c20 = sigmoid_f(gF0) * creg0 + sigmoid_f(gI0) * tanh_f(gG0);
    float h20 = sigmoid_f(gO0) * tanh_f(c20);
    float c21 = sigmoid_f(gF1) * creg1 + sigmoid_f(gI1) * tanh_f(gG1);
    float h21 = sigmoid_f(gO1) * tanh_f(c21);
    creg0 = c20;
    creg1 = c21;
    float s10 = h20, s20 = h20 * h20, s11 = h21, s21 = h21 * h21;
#pragma unroll
    for (int off = 32; off; off >>= 1) {
      s10 += __shfl_xor(s10, off, 64);
      s20 += __shfl_xor(s20, off, 64);
      s11 += __shfl_xor(s11, off, 64);
      s21 += __shfl_xor(s21, off, 64);
    }
    float mu0 = s10 * (1.f / 64.f), var0 = fmaf(-mu0, mu0, s20 * (1.f / 64.f));
    float mu1 = s11 * (1.f / 64.f), var1 = fmaf(-mu1, mu1, s21 * (1.f / 64.f));
    float hn0 = gam0 * (h20 - mu0) * rsqrtf(var0 + BN_EPS) + bet0;
    float hn1 = gam1 * (h21 - mu1) * rsqrtf(var1 + BN_EPS) + bet1;
    pool0 = fmaxf(pool0, hn0 * msk0);
    pool1 = fmaxf(pool1, hn1 * msk1);
    pkbuf[b][w] = (unsigned)tobf(h20) | ((unsigned)tobf(h21) << 16);
    __syncthreads();

    // ---- wave2: single full-line 1KB publish; drain covers ONLY the
    // publish (x-prefetch has NOT been issued yet); slot fire-and-forget ----
    if (w == 2) {
      u32x4 pv = {pkbuf[l][0], pkbuf[l][1], pkbuf[l][2], pkbuf[l][3]};
      st4_sc_nd(hnx + (size_t)blk * 512 + l * 8, pv);
      WAITV(0);  // 1 LLC RT: publish ack'd
      if (l == 0) st_sc32_nd(&slots[blk], (unsigned)(s + 1));
    }

    // ---- x prefetch for s+1, issued at loop bottom: AFTER wave2's drain,
    // with the entire next poll window to land ----
    {
      int sx = (s + 1 < TT) ? s + 1 : s;  // uniform ledger on last iter
      const unsigned short* px = xbf + ((size_t)sx * BB + row) * XPAD + lk16 * 8;
#pragma unroll
      for (int i = 0; i < KS_X; ++i) ldA_nc(px + i * 32, xa[i]);
    }
  }

  // ---- per-block FC partial ----
  red_s[w][b] = pool0 * fw0 + pool1 * fw1;
  __syncthreads();
  if (tid < BB) {
    float part = red_s[0][tid] + red_s[1][tid] + red_s[2][tid] + red_s[3][tid];
    st_sc32(&partial[(size_t)tid * NBLK + blk], __float_as_uint(part));
  }
  __syncthreads();
  if (tid == 0) st_sc32_nd(&slots[blk], (unsigned)(TT + 2));
  if (blk != 0) return;

  // ---- block 0: final reduction + loss ----
  poll_ge(slots, tid, (unsigned)(TT + 2));
  {
    int fb = tid & 63, q = tid >> 6;
    const float* pp = partial + ((size_t)fb * NBLK + q * 32);
    f32x4 v0, v1, v2, v3, v4, v5, v6, v7;
    ld4_sc(pp + 0, v0);  ld4_sc(pp + 4, v1);  ld4_sc(pp + 8, v2);  ld4_sc(pp + 12, v3);
    ld4_sc(pp + 16, v4); ld4_sc(pp + 20, v5); ld4_sc(pp + 24, v6); ld4_sc(pp + 28, v7);
    WAITV(0);
    float sum = v0.x + v0.y + v0.z + v0.w + v1.x + v1.y + v1.z + v1.w +
                v2.x + v2.y + v2.z + v2.w + v3.x + v3.y + v3.z + v3.w +
                v4.x + v4.y + v4.z + v4.w + v5.x + v5.y + v5.z + v5.w +
                v6.x + v6.y + v6.z + v6.w + v7.x + v7.y + v7.z + v7.w;
    red_s[q][fb] = sum;
  }
  __syncthreads();
  if (tid < BB) {
    float z = red_s[0][tid] + red_s[1][tid] + red_s[2][tid] + red_s[3][tid] + fcb[0];
    outp[1 + tid] = z;
    float sp = fmaxf(z, 0.f) + log1pf(__expf(-fabsf(z)));
    float lt = sp - z * tlbl[tid];
#pragma unroll
    for (int off = 32; off; off >>= 1) lt += __shfl_xor(lt, off, 64);
    if (tid == 0) outp[0] = lt * (1.f / 64.f);
  }
}

extern "C" void kernel_launch(void* const* d_in, const int* in_sizes, int n_in,
                              void* d_out, int out_size, void* d_ws, size_t ws_size,
                              hipStream_t stream) {
  const float* x = (const float*)d_in[0];
  const float* tlbl = (const float*)d_in[1];
  const float* maskp = (const float*)d_in[2];
  const float* Wih = (const float*)d_in[3];
  const float* Whh = (const float*)d_in[4];
  const float* bih = (const float*)d_in[5];
  const float* bhh = (const float*)d_in[6];
  const float* gammap = (const float*)d_in[7];
  const float* betap = (const float*)d_in[8];
  const float* fcw = (const float*)d_in[9];
  const float* fcb = (const float*)d_in[10];
  float* outp = (float*)d_out;

  // ws: slots(512B)+pad @0 | hbuf 2x128KB @4KB | partial 32KB | xbf 20.5MB
  unsigned* slots = (unsigned*)d_ws;
  unsigned short* hbuf = (unsigned short*)((char*)d_ws + 4096);
  float* partial = (float*)((char*)d_ws + 4096 + 2 * BB * HH * 2);
  unsigned short* xbf =
      (unsigned short*)((char*)d_ws + 4096 + 2 * BB * HH * 2 + BB * NBLK * 4);

  // zero slots + h image 0 (contiguous from ws base: 4096 + 128KB)
  int ndw = (4096 + BB * HH * 2) / 4;
  hipLaunchKernelGGL(init_k, dim3(64), dim3(NTH), 0, stream, (unsigned*)d_ws, ndw);
  hipLaunchKernelGGL(xcvt_k, dim3(2048), dim3(NTH), 0, stream, x, xbf);
  hipLaunchKernelGGL(lstm_mfma, dim3(NBLK), dim3(NTH), 0, stream,
                     Wih, Whh, bih, bhh, gammap, betap, maskp, tlbl, fcw, fcb,
                     xbf, hbuf, partial, slots, outp);
}

// Round 13
// 2658.484 us; speedup vs baseline: 2.1149x; 1.4520x over previous
//
#include <hip/hip_runtime.h>
#include <cstddef>
#include <cstdint>

#define BB 64
#define TT 512
#define HH 1024
#define DD 300
#define NTH 256
#define NBLK 128
#define HB 8                  // h-indices per block
#define XPAD 320              // x K padded to 10*32
#define KS_X 10
#define KS_H 32
#define BN_EPS 1e-5f

typedef short short8 __attribute__((ext_vector_type(8)));
typedef float f32x4 __attribute__((ext_vector_type(4)));
typedef unsigned u32x2 __attribute__((ext_vector_type(2)));
typedef unsigned u32x4 __attribute__((ext_vector_type(4)));

__device__ __forceinline__ float sigmoid_f(float v) {
  v = fminf(fmaxf(v, -30.f), 30.f);
  return 1.f / (1.f + __expf(-v));
}
__device__ __forceinline__ float tanh_f(float v) {
  float e = __expf(fminf(fmaxf(2.f * v, -30.f), 30.f));
  return (e - 1.f) / (e + 1.f);
}
__device__ __forceinline__ unsigned short tobf(float f) {
  unsigned u = __float_as_uint(f);
  u += 0x7fffu + ((u >> 16) & 1u);
  return (unsigned short)(u >> 16);
}

// ---- all in-loop vmem is inline asm so counted-vmcnt bookkeeping stays exact
__device__ __forceinline__ void ldA_sc(const void* p, short8& d) {
  asm volatile("global_load_dwordx4 %0, %1, off sc0 sc1"
               : "=v"(d) : "v"(p) : "memory");
}
__device__ __forceinline__ void ldA_nc(const void* p, short8& d) {
  asm volatile("global_load_dwordx4 %0, %1, off"
               : "=v"(d) : "v"(p) : "memory");
}
__device__ __forceinline__ void ld4_sc(const void* p, f32x4& d) {
  asm volatile("global_load_dwordx4 %0, %1, off sc0 sc1"
               : "=v"(d) : "v"(p) : "memory");
}
__device__ __forceinline__ u32x2 ld2w_sc(const void* p) {
  u32x2 v;
  asm volatile("global_load_dwordx2 %0, %1, off sc0 sc1\n\ts_waitcnt vmcnt(0)"
               : "=v"(v) : "v"(p) : "memory");
  return v;
}
__device__ __forceinline__ void st_sc32(void* p, unsigned v) {  // with drain
  asm volatile("global_store_dword %0, %1, off sc0 sc1\n\ts_waitcnt vmcnt(0)"
               :: "v"(p), "v"(v) : "memory");
}
__device__ __forceinline__ void st_sc32_nd(void* p, unsigned v) {  // no drain
  asm volatile("global_store_dword %0, %1, off sc0 sc1"
               :: "v"(p), "v"(v) : "memory");
}
__device__ __forceinline__ void st4_sc_nd(void* p, u32x4 v) {  // no drain
  asm volatile("global_store_dwordx4 %0, %1, off sc0 sc1"
               :: "v"(p), "v"(v) : "memory");
}
#define WAITV(N)                                                   \
  do {                                                             \
    asm volatile("s_waitcnt vmcnt(" #N ")" ::: "memory");          \
    __builtin_amdgcn_sched_barrier(0);                             \
  } while (0)

__device__ __forceinline__ f32x4 mfma16(short8 a, short8 b, f32x4 c) {
  return __builtin_amdgcn_mfma_f32_16x16x32_bf16(a, b, c, 0, 0, 0);
}

// wave0-only poll: lane i checks slots[2i], slots[2i+1]. Drained probes.
// PRECONDITION (this round's fix): wave0 calls this only AFTER its own
// block's slot is raised -> first probe can succeed; no own-slot race.
__device__ __forceinline__ void poll_ge(const unsigned* slots, int tid, unsigned ep) {
  int it = 0;
  for (;;) {
    int ok = 1;
    if (tid < 64) {
      u32x2 v = ld2w_sc(&slots[2 * tid]);
      ok = (v.x >= ep && v.y >= ep) ? 1 : 0;
    }
    if (__syncthreads_and(ok)) break;
    if (++it > (1 << 20)) break;  // valve: fail visibly, never hang
    if (it > 2) __builtin_amdgcn_s_sleep(1);
  }
}

__global__ void init_k(unsigned* __restrict__ base, int ndw) {
  int idx = blockIdx.x * blockDim.x + threadIdx.x;
  for (int i = idx; i < ndw; i += gridDim.x * blockDim.x) st_sc32(base + i, 0u);
}

// x [b][t][d] f32 -> xbf [t][b][XPAD] bf16 (zero-padded)
__global__ void xcvt_k(const float* __restrict__ x, unsigned short* __restrict__ xbf) {
  const int total = TT * BB * XPAD;
  for (int idx = blockIdx.x * blockDim.x + threadIdx.x; idx < total;
       idx += gridDim.x * blockDim.x) {
    int kx = idx % XPAD;
    int tb = idx / XPAD;
    int b = tb % BB, t = tb / BB;
    float v = (kx < DD) ? x[(size_t)b * (TT * DD) + (size_t)t * DD + kx] : 0.f;
    xbf[idx] = tobf(v);
  }
}

__global__ void __launch_bounds__(NTH, 1)
lstm_mfma(const float* __restrict__ Wih, const float* __restrict__ Whh,
          const float* __restrict__ bih, const float* __restrict__ bhh,
          const float* __restrict__ gammap, const float* __restrict__ betap,
          const float* __restrict__ maskp, const float* __restrict__ tlbl,
          const float* __restrict__ fcw, const float* __restrict__ fcb,
          const unsigned short* __restrict__ xbf, unsigned short* __restrict__ hbuf,
          float* __restrict__ partial, unsigned* __restrict__ slots,
          float* __restrict__ outp) {
  // B-operand fragments: Wlds[nt][ks][lane] = 8 bf16 of
  // B[k = ks*32 + (lane>>4)*8 + e][col = nt*16 + (lane&15)].
  // ks 0..31 = W_hh, 32..41 = W_ih (zero-padded). Lane-linear ds_read_b128.
  __shared__ short8 Wlds[2][KS_H + KS_X][64];  // 84 KB
  __shared__ float Cs[64][33];                 // 8.4 KB (+1 pad)
  __shared__ unsigned pkbuf[BB][4];            // 1 KB staged publish
  __shared__ float red_s[4][64];               // 1 KB

  const int tid = threadIdx.x;
  const int w = tid >> 6, l = tid & 63;
  const int blk = blockIdx.x;
  const int hb0 = blk * HB;

  // ---- stage W as bf16 fragments (once) ----
  for (int idx = tid; idx < 2 * (KS_H + KS_X) * 64; idx += NTH) {
    int nt = idx / ((KS_H + KS_X) * 64);
    int rem = idx % ((KS_H + KS_X) * 64);
    int ks = rem >> 6, ll = rem & 63;
    int colq = nt * 16 + (ll & 15);
    int g = colq >> 3, j = colq & 7;
    int r = g * HH + hb0 + j;
    int k0 = (ll >> 4) * 8;
    float v[8];
    if (ks < KS_H) {
      const float* src = Whh + (size_t)r * HH + ks * 32 + k0;
      f32x4 u0 = *(const f32x4*)src;
      f32x4 u1 = *(const f32x4*)(src + 4);
      v[0] = u0.x; v[1] = u0.y; v[2] = u0.z; v[3] = u0.w;
      v[4] = u1.x; v[5] = u1.y; v[6] = u1.z; v[7] = u1.w;
    } else {
      int d0 = (ks - KS_H) * 32 + k0;
#pragma unroll
      for (int e = 0; e < 8; ++e)
        v[e] = (d0 + e < DD) ? Wih[(size_t)r * DD + d0 + e] : 0.f;
    }
    short8 pk;
#pragma unroll
    for (int e = 0; e < 8; ++e) pk[e] = (short)tobf(v[e]);
    Wlds[nt][ks][ll] = pk;
  }

  // ---- MFMA roles: wave = M-tile; computes both N-tiles ----
  const int row = w * 16 + (l & 15);
  const int lk16 = (l >> 4);

  // per-column combined bias (folded into acc init)
  const int cq = l & 15;
  const float bcol0 = bih[(cq >> 3) * HH + hb0 + (cq & 7)] +
                      bhh[(cq >> 3) * HH + hb0 + (cq & 7)];
  const float bcol1 = bih[(2 + (cq >> 3)) * HH + hb0 + (cq & 7)] +
                      bhh[(2 + (cq >> 3)) * HH + hb0 + (cq & 7)];

  // ---- pointwise roles: lane = batch, wave w -> h-sub j0=2w, j1=2w+1 ----
  const int b = l, j0 = 2 * w, j1 = 2 * w + 1;
  const float gam0 = gammap[hb0 + j0], gam1 = gammap[hb0 + j1];
  const float bet0 = betap[hb0 + j0], bet1 = betap[hb0 + j1];
  const float msk0 = maskp[(size_t)b * HH + hb0 + j0];
  const float msk1 = maskp[(size_t)b * HH + hb0 + j1];
  const float fw0 = fcw[hb0 + j0], fw1 = fcw[hb0 + j1];
  float creg0 = 0.f, creg1 = 0.f;
  float pool0 = -3.4e38f, pool1 = -3.4e38f;

  // prologue: issue x-loads for s=0
  short8 xa[KS_X];
  {
    const unsigned short* px = xbf + ((size_t)0 * BB + row) * XPAD + lk16 * 8;
#pragma unroll
    for (int i = 0; i < KS_X; ++i) ldA_nc(px + i * 32, xa[i]);
  }
  __syncthreads();  // Wlds visible

  for (int s = 0; s < TT; ++s) {
    const unsigned short* hc = hbuf + (size_t)(s & 1) * (BB * HH);
    unsigned short* hnx = hbuf + (size_t)((s + 1) & 1) * (BB * HH);

    // wait for h_s publication (s=0 passes immediately; own slot already
    // raised by THIS wave0 before it entered the poll -> no own-slot race)
    poll_ge(slots, tid, (unsigned)s);

    // issue ALL 32 h A-frag loads (addr = hc + (ks*4 + lk16)*512 + row*8)
    const unsigned short* ph = hc + (size_t)lk16 * 512 + row * 8;
    short8 ha[KS_H];
#pragma unroll
    for (int i = 0; i < KS_H; ++i) ldA_sc(ph + i * 2048, ha[i]);

    // Per-wave queues here: w0 = [h32] (x+pub drained at its WAITV(0), slot
    // drained by poll probe), w1-3 = [x10, h32] = 42 -> WAITV(32) retires x
    // exactly (x had pointwise+publish+poll window to land).
    WAITV(32);

    // x-MFMAs while h chunk0 is in flight; 4 independent acc chains
    f32x4 acc0a = {bcol0, bcol0, bcol0, bcol0}, acc0b = {0.f, 0.f, 0.f, 0.f};
    f32x4 acc1a = {bcol1, bcol1, bcol1, bcol1}, acc1b = {0.f, 0.f, 0.f, 0.f};
#pragma unroll
    for (int i = 0; i < KS_X; i += 2) {
      acc0a = mfma16(xa[i], Wlds[0][KS_H + i][l], acc0a);
      acc1a = mfma16(xa[i], Wlds[1][KS_H + i][l], acc1a);
      acc0b = mfma16(xa[i + 1], Wlds[0][KS_H + i + 1][l], acc0b);
      acc1b = mfma16(xa[i + 1], Wlds[1][KS_H + i + 1][l], acc1b);
    }
    WAITV(24);  // h chunk0 (loads 0..7) done
#pragma unroll
    for (int i = 0; i < 8; i += 2) {
      acc0a = mfma16(ha[i], Wlds[0][i][l], acc0a);
      acc1a = mfma16(ha[i], Wlds[1][i][l], acc1a);
      acc0b = mfma16(ha[i + 1], Wlds[0][i + 1][l], acc0b);
      acc1b = mfma16(ha[i + 1], Wlds[1][i + 1][l], acc1b);
    }
    WAITV(16);  // chunk1
#pragma unroll
    for (int i = 8; i < 16; i += 2) {
      acc0a = mfma16(ha[i], Wlds[0][i][l], acc0a);
      acc1a = mfma16(ha[i], Wlds[1][i][l], acc1a);
      acc0b = mfma16(ha[i + 1], Wlds[0][i + 1][l], acc0b);
      acc1b = mfma16(ha[i + 1], Wlds[1][i + 1][l], acc1b);
    }
    WAITV(8);  // chunk2
#pragma unroll
    for (int i = 16; i < 24; i += 2) {
      acc0a = mfma16(ha[i], Wlds[0][i][l], acc0a);
      acc1a = mfma16(ha[i], Wlds[1][i][l], acc1a);
      acc0b = mfma16(ha[i + 1], Wlds[0][i + 1][l], acc0b);
      acc1b = mfma16(ha[i + 1], Wlds[1][i + 1][l], acc1b);
    }
    WAITV(0);  // chunk3
#pragma unroll
    for (int i = 24; i < 32; i += 2) {
      acc0a = mfma16(ha[i], Wlds[0][i][l], acc0a);
      acc1a = mfma16(ha[i], Wlds[1][i][l], acc1a);
      acc0b = mfma16(ha[i + 1], Wlds[0][i + 1][l], acc0b);
      acc1b = mfma16(ha[i + 1], Wlds[1][i + 1][l], acc1b);
    }
    f32x4 acc0 = acc0a + acc0b, acc1 = acc1a + acc1b;

    // ---- C exchange via LDS (C: col=lane&15, row=(lane>>4)*4+r) ----
    {
      int crow = w * 16 + (l >> 4) * 4;
      int cc0 = (l & 15), cc1 = 16 + (l & 15);
#pragma unroll
      for (int r = 0; r < 4; ++r) {
        Cs[crow + r][cc0] = acc0[r];
        Cs[crow + r][cc1] = acc1[r];
      }
    }
    __syncthreads();

    // ---- x prefetch for s+1 (r5's proven position: has pointwise+publish
    // +poll window to land; retired at wave0's WAITV(0) / others' WAITV(32))
    {
      int sx = (s + 1 < TT) ? s + 1 : s;  // uniform ledger on last iter
      const unsigned short* px = xbf + ((size_t)sx * BB + row) * XPAD + lk16 * 8;
#pragma unroll
      for (int i = 0; i < KS_X; ++i) ldA_nc(px + i * 32, xa[i]);
    }

    // ---- pointwise-lite: ONLY what the recurrence needs (BN deferred) ----
    float gI0 = Cs[b][j0],      gF0 = Cs[b][8 + j0];
    float gG0 = Cs[b][16 + j0], gO0 = Cs[b][24 + j0];
    float gI1 = Cs[b][j1],      gF1 = Cs[b][8 + j1];
    float gG1 = Cs[b][16 + j1], gO1 = Cs[b][24 + j1];
    float c20 = sigmoid_f(gF0) * creg0 + sigmoid_f(gI0) * tanh_f(gG0);
    float h20 = sigmoid_f(gO0) * tanh_f(c20);
    float c21 = sigmoid_f(gF1) * creg1 + sigmoid_f(gI1) * tanh_f(gG1);
    float h21 = sigmoid_f(gO1) * tanh_f(c21);
    creg0 = c20;
    creg1 = c21;
    pkbuf[b][w] = (unsigned)tobf(h20) | ((unsigned)tobf(h21) << 16);
    __syncthreads();

    // ---- wave0: full-line 1KB publish + drain + fire-forget slot, THEN it
    // enters the poll (own slot guaranteed raised before first probe) ----
    if (w == 0) {
      u32x4 pv = {pkbuf[l][0], pkbuf[l][1], pkbuf[l][2], pkbuf[l][3]};
      st4_sc_nd(hnx + (size_t)blk * 512 + l * 8, pv);
      WAITV(0);  // drains publish + this wave's x-prefetch (1 LLC RT)
      if (l == 0) st_sc32_nd(&slots[blk], (unsigned)(s + 1));
    }

    // ---- BN + pool: OFF the critical chain (waves 1-3 run this under
    // wave0's publish drain; wave0 runs it after the slot raise) ----
    {
      float s10 = h20, s20 = h20 * h20, s11 = h21, s21 = h21 * h21;
#pragma unroll
      for (int off = 32; off; off >>= 1) {
        s10 += __shfl_xor(s10, off, 64);
        s20 += __shfl_xor(s20, off, 64);
        s11 += __shfl_xor(s11, off, 64);
        s21 += __shfl_xor(s21, off, 64);
      }
      float mu0 = s10 * (1.f / 64.f), var0 = fmaf(-mu0, mu0, s20 * (1.f / 64.f));
      float mu1 = s11 * (1.f / 64.f), var1 = fmaf(-mu1, mu1, s21 * (1.f / 64.f));
      float hn0 = gam0 * (h20 - mu0) * rsqrtf(var0 + BN_EPS) + bet0;
      float hn1 = gam1 * (h21 - mu1) * rsqrtf(var1 + BN_EPS) + bet1;
      pool0 = fmaxf(pool0, hn0 * msk0);
      pool1 = fmaxf(pool1, hn1 * msk1);
    }
  }

  // ---- per-block FC partial ----
  red_s[w][b] = pool0 * fw0 + pool1 * fw1;
  __syncthreads();
  if (tid < BB) {
    float part = red_s[0][tid] + red_s[1][tid] + red_s[2][tid] + red_s[3][tid];
    st_sc32(&partial[(size_t)tid * NBLK + blk], __float_as_uint(part));
  }
  __syncthreads();
  if (tid == 0) st_sc32_nd(&slots[blk], (unsigned)(TT + 2));
  if (blk != 0) return;

  // ---- block 0: final reduction + loss ----
  poll_ge(slots, tid, (unsigned)(TT + 2));
  {
    int fb = tid & 63, q = tid >> 6;
    const float* pp = partial + ((size_t)fb * NBLK + q * 32);
    f32x4 v0, v1, v2, v3, v4, v5, v6, v7;
    ld4_sc(pp + 0, v0);  ld4_sc(pp + 4, v1);  ld4_sc(pp + 8, v2);  ld4_sc(pp + 12, v3);
    ld4_sc(pp + 16, v4); ld4_sc(pp + 20, v5); ld4_sc(pp + 24, v6); ld4_sc(pp + 28, v7);
    WAITV(0);
    float sum = v0.x + v0.y + v0.z + v0.w + v1.x + v1.y + v1.z + v1.w +
                v2.x + v2.y + v2.z + v2.w + v3.x + v3.y + v3.z + v3.w +
                v4.x + v4.y + v4.z + v4.w + v5.x + v5.y + v5.z + v5.w +
                v6.x + v6.y + v6.z + v6.w + v7.x + v7.y + v7.z + v7.w;
    red_s[q][fb] = sum;
  }
  __syncthreads();
  if (tid < BB) {
    float z = red_s[0][tid] + red_s[1][tid] + red_s[2][tid] + red_s[3][tid] + fcb[0];
    outp[1 + tid] = z;
    float sp = fmaxf(z, 0.f) + log1pf(__expf(-fabsf(z)));
    float lt = sp - z * tlbl[tid];
#pragma unroll
    for (int off = 32; off; off >>= 1) lt += __shfl_xor(lt, off, 64);
    if (tid == 0) outp[0] = lt * (1.f / 64.f);
  }
}

extern "C" void kernel_launch(void* const* d_in, const int* in_sizes, int n_in,
                              void* d_out, int out_size, void* d_ws, size_t ws_size,
                              hipStream_t stream) {
  const float* x = (const float*)d_in[0];
  const float* tlbl = (const float*)d_in[1];
  const float* maskp = (const float*)d_in[2];
  const float* Wih = (const float*)d_in[3];
  const float* Whh = (const float*)d_in[4];
  const float* bih = (const float*)d_in[5];
  const float* bhh = (const float*)d_in[6];
  const float* gammap = (const float*)d_in[7];
  const float* betap = (const float*)d_in[8];
  const float* fcw = (const float*)d_in[9];
  const float* fcb = (const float*)d_in[10];
  float* outp = (float*)d_out;

  // ws: slots(512B)+pad @0 | hbuf 2x128KB @4KB | partial 32KB | xbf 20.5MB
  unsigned* slots = (unsigned*)d_ws;
  unsigned short* hbuf = (unsigned short*)((char*)d_ws + 4096);
  float* partial = (float*)((char*)d_ws + 4096 + 2 * BB * HH * 2);
  unsigned short* xbf =
      (unsigned short*)((char*)d_ws + 4096 + 2 * BB * HH * 2 + BB * NBLK * 4);

  // zero slots + h image 0 (contiguous from ws base: 4096 + 128KB)
  int ndw = (4096 + BB * HH * 2) / 4;
  hipLaunchKernelGGL(init_k, dim3(64), dim3(NTH), 0, stream, (unsigned*)d_ws, ndw);
  hipLaunchKernelGGL(xcvt_k, dim3(2048), dim3(NTH), 0, stream, x, xbf);
  hipLaunchKernelGGL(lstm_mfma, dim3(NBLK), dim3(NTH), 0, stream,
                     Wih, Whh, bih, bhh, gammap, betap, maskp, tlbl, fcw, fcb,
                     xbf, hbuf, partial, slots, outp);
}